// Round 1
// baseline (1039.141 us; speedup 1.0000x reference)
//
#include <hip/hip_runtime.h>
#include <stdint.h>

#define PN 4
#define NN 65536
#define DD 128
#define OO 128
#define EE 500000
#define MM 32768
#define NW 245       // WGs per block for bucketing: ceil(500000/2048)

typedef __attribute__((ext_vector_type(8))) short short8;
typedef __attribute__((ext_vector_type(4))) float floatx4;

__device__ __forceinline__ unsigned short f2bf(float f) {
  unsigned u = __float_as_uint(f);
  u += 0x7fffu + ((u >> 16) & 1u);
  return (unsigned short)(u >> 16);
}
__device__ __forceinline__ float bfhi2f(unsigned u) { return __uint_as_float(u & 0xffff0000u); }
__device__ __forceinline__ float bflo2f(unsigned u) { return __uint_as_float(u << 16); }

// block b = s*4+d; diag blocks are b in {0,5,10,15}
__device__ __forceinline__ long rowbase(int b) {
  int diagb = (b + 4) / 5;
  int offb = b - diagb;
  return (long)diagb * NN + (long)offb * MM;
}

// ---- fp32 -> bf16 conversion of feats ----
__global__ __launch_bounds__(256) void cvt_kernel(const float* __restrict__ f,
                                                  unsigned short* __restrict__ o) {
  size_t i = (size_t)blockIdx.x * blockDim.x + threadIdx.x;
  float4 v = ((const float4*)f)[i];
  uint2 r;
  r.x = ((unsigned)f2bf(v.y) << 16) | f2bf(v.x);
  r.y = ((unsigned)f2bf(v.w) << 16) | f2bf(v.z);
  ((uint2*)o)[i] = r;
}

// ---- pack W_self/W_neigh to bf16, col-major [mat][s][col][k] ----
__global__ __launch_bounds__(256) void packW_kernel(const float* __restrict__ Ws,
                                                    const float* __restrict__ Wn,
                                                    unsigned short* __restrict__ Wp) {
  int i = blockIdx.x * 256 + threadIdx.x;   // 2*4*128*128 = 131072
  int k = i & 127;
  int col = (i >> 7) & 127;
  int s = (i >> 14) & 3;
  int mat = i >> 16;
  const float* W = mat ? Wn : Ws;
  Wp[i] = f2bf(W[((size_t)s * DD + k) * OO + col]);
}

// ---- R1: per-WG coarse histogram (dst>>8), LDS only, coalesced matrix write ----
__global__ __launch_bounds__(256) void bucket_count(const int* __restrict__ edst,
                                                    int* __restrict__ mat) {
  __shared__ int hist[256];
  int b = blockIdx.y, w = blockIdx.x, t = threadIdx.x;
  hist[t] = 0;
  __syncthreads();
  size_t ebase = (size_t)b * EE;
#pragma unroll
  for (int k = 0; k < 8; ++k) {
    int e = w * 2048 + k * 256 + t;
    if (e < EE) atomicAdd(&hist[edst[ebase + e] >> 8], 1);
  }
  __syncthreads();
  mat[((size_t)b * NW + w) * 256 + t] = hist[t];
}

// ---- R2a: exclusive scan of mat over WG axis (per b,beta); totals per bucket ----
__global__ __launch_bounds__(256) void bucket_colscan(int* __restrict__ mat,
                                                      int* __restrict__ btot) {
  int t = threadIdx.x;
  int wid = blockIdx.x * 4 + (t >> 6);   // 4096 waves = 16 b * 256 beta
  int l = t & 63;
  int b = wid >> 8, beta = wid & 255;
  int run = 0;
  for (int c = 0; c < 4; ++c) {
    int w = c * 64 + l;
    size_t idx = ((size_t)b * NW + w) * 256 + beta;
    int v = (w < NW) ? mat[idx] : 0;
    int x = v;
#pragma unroll
    for (int off = 1; off < 64; off <<= 1) {
      int y = __shfl_up(x, off);
      if (l >= off) x += y;
    }
    if (w < NW) mat[idx] = run + x - v;
    run += __shfl(x, 63);
  }
  if (l == 0) btot[b * 256 + beta] = run;
}

// ---- R2b: per-block exclusive scan of 256 bucket totals -> bucket bases ----
__global__ __launch_bounds__(256) void bucket_base(const int* __restrict__ btot,
                                                   int* __restrict__ bbase) {
  __shared__ int sc[256];
  int b = blockIdx.x, t = threadIdx.x;
  int v = btot[b * 256 + t];
  sc[t] = v;
  __syncthreads();
  for (int off = 1; off < 256; off <<= 1) {
    int x = (t >= off) ? sc[t - off] : 0;
    __syncthreads();
    sc[t] += x;
    __syncthreads();
  }
  bbase[b * 256 + t] = sc[t] - v;
}

// ---- R3: scatter edges into coarse-bucket-sorted tmp via LDS cursors ----
__global__ __launch_bounds__(256) void bucket_scatter(const int* __restrict__ esrc,
                                                      const int* __restrict__ edst,
                                                      const int* __restrict__ mat,
                                                      const int* __restrict__ bbase,
                                                      uint2* __restrict__ tmp) {
  __shared__ int cur[256];
  int b = blockIdx.y, w = blockIdx.x, t = threadIdx.x;
  cur[t] = bbase[b * 256 + t] + mat[((size_t)b * NW + w) * 256 + t];
  __syncthreads();
  size_t ebase = (size_t)b * EE;
#pragma unroll
  for (int k = 0; k < 8; ++k) {
    int e = w * 2048 + k * 256 + t;
    if (e < EE) {
      int dv = edst[ebase + e];
      int sv = esrc[ebase + e];
      int p = atomicAdd(&cur[dv >> 8], 1);
      tmp[ebase + p] = (uint2){(unsigned)dv, (unsigned)sv};
    }
  }
}

// ---- R4: per (b, coarse bucket): fine CSR + deg + offs, all LDS-local ----
__global__ __launch_bounds__(256) void csr_build(const uint2* __restrict__ tmp,
                                                 const int* __restrict__ btot,
                                                 const int* __restrict__ bbase,
                                                 int* __restrict__ deg,
                                                 int* __restrict__ offs,
                                                 int* __restrict__ csr) {
  __shared__ int hist[256], sc[256], cur[256];
  int b = blockIdx.y, beta = blockIdx.x, t = threadIdx.x;
  int cnt = btot[b * 256 + beta];
  int segbase = bbase[b * 256 + beta];
  hist[t] = 0;
  __syncthreads();
  size_t tbase = (size_t)b * EE + segbase;
  for (int i = t; i < cnt; i += 256) atomicAdd(&hist[tmp[tbase + i].x & 255], 1);
  __syncthreads();
  sc[t] = hist[t];
  __syncthreads();
  for (int off = 1; off < 256; off <<= 1) {
    int x = (t >= off) ? sc[t - off] : 0;
    __syncthreads();
    sc[t] += x;
    __syncthreads();
  }
  int excl = sc[t] - hist[t];
  int v = beta * 256 + t;
  deg[b * NN + v] = hist[t];
  offs[b * NN + v] = segbase + excl;
  cur[t] = excl;
  __syncthreads();
  for (int i = t; i < cnt; i += 256) {
    uint2 pr = tmp[tbase + i];
    int p = atomicAdd(&cur[pr.x & 255], 1);
    csr[(size_t)b * EE + segbase + p] = (int)pr.y;
  }
}

// ---- mean aggregation: one wave per dst row ----
// Key structure: the CSR segment and every gathered row index are wave-uniform.
// Indices are loaded per-lane once per 64 edges, then moved to SGPRs via
// v_readlane so the feature-row base is SALU-computed (uniform base + l*4
// voffset) -- no ds_bpermute, no per-lane 64-bit address chain.
__global__ __launch_bounds__(256) void agg_kernel(const unsigned short* __restrict__ featsbf,
                                                  const int* __restrict__ csr,
                                                  const int* __restrict__ offs,
                                                  const int* __restrict__ deg,
                                                  unsigned short* __restrict__ hbuf) {
  int b = blockIdx.y;
  int s = b >> 2, d = b & 3;
  int num_dst = (s == d) ? NN : MM;
  int v = blockIdx.x * 4 + (threadIdx.x >> 6);
  if (v >= num_dst) return;
  int l = threadIdx.x & 63;
  const unsigned* F = (const unsigned*)(featsbf + (size_t)s * NN * DD);
  int o  = __builtin_amdgcn_readfirstlane(offs[b * NN + v]);
  int dg = __builtin_amdgcn_readfirstlane(deg[b * NN + v]);
  const int* cs = csr + (size_t)b * EE + o;   // wave-uniform pointer

  float alo[4] = {0.f, 0.f, 0.f, 0.f};
  float ahi[4] = {0.f, 0.f, 0.f, 0.f};

  for (int base = 0; base < dg; base += 64) {
    int rem = dg - base;
    int cnt = rem < 64 ? rem : 64;
    int myidx = (l < cnt) ? cs[base + l] : 0;
    int j = 0;
    for (; j + 8 <= cnt; j += 8) {
      unsigned p[8];
#pragma unroll
      for (int q = 0; q < 8; ++q) {
        int idx = __builtin_amdgcn_readlane(myidx, j + q);   // SGPR index
        p[q] = F[(size_t)idx * 64 + l];                      // uniform base + l*4
      }
#pragma unroll
      for (int q = 0; q < 8; ++q) { alo[q & 3] += bflo2f(p[q]); ahi[q & 3] += bfhi2f(p[q]); }
    }
    for (; j + 4 <= cnt; j += 4) {
      unsigned p[4];
#pragma unroll
      for (int q = 0; q < 4; ++q) {
        int idx = __builtin_amdgcn_readlane(myidx, j + q);
        p[q] = F[(size_t)idx * 64 + l];
      }
#pragma unroll
      for (int q = 0; q < 4; ++q) { alo[q] += bflo2f(p[q]); ahi[q] += bfhi2f(p[q]); }
    }
    for (; j < cnt; ++j) {
      int idx = __builtin_amdgcn_readlane(myidx, j);
      unsigned p = F[(size_t)idx * 64 + l];
      alo[0] += bflo2f(p); ahi[0] += bfhi2f(p);
    }
  }

  float a0 = (alo[0] + alo[1]) + (alo[2] + alo[3]);
  float a1 = (ahi[0] + ahi[1]) + (ahi[2] + ahi[3]);
  float inv = 1.0f / (float)(dg > 0 ? dg : 1);
  a0 *= inv; a1 *= inv;
  unsigned pk = ((unsigned)f2bf(a1) << 16) | f2bf(a0);
  ((unsigned*)hbuf)[(rowbase(b) + v) * 64 + l] = pk;
}

// ---- fused dual GEMM + merge epilogue ----
// mfma_f32_16x16x32_bf16: A[m=l&15][k=(l>>4)*8+j], B[k][n=l&15], C col=l&15, row=(l>>4)*4+reg
__global__ __launch_bounds__(256) void gemm_kernel(const unsigned short* __restrict__ featsbf,
                                                   const unsigned short* __restrict__ hbuf,
                                                   const unsigned short* __restrict__ Wpack,
                                                   const float* __restrict__ bias,
                                                   const int* __restrict__ merge,
                                                   float* __restrict__ out,
                                                   int offdiag) {
  int w = threadIdx.x >> 6;
  int l = threadIdx.x & 63;
  int s, d;
  if (!offdiag) { d = blockIdx.y; s = d; }
  else { int y = blockIdx.y; s = y / 3; int r = y % 3; d = r + (r >= s ? 1 : 0); }
  int b = s * 4 + d;
  int row0 = blockIdx.x * 64;
  int kq = l >> 4;
  int m16 = l & 15;
  int n0 = w * 32;

  const unsigned short* Aself = featsbf + (size_t)s * NN * DD;
  const unsigned short* Ah = hbuf + (size_t)rowbase(b) * DD;

  short8 bfrag[2][4][2];
#pragma unroll
  for (int mat = 0; mat < 2; ++mat) {
    const unsigned short* WT = Wpack + ((size_t)(mat * PN + s) * OO) * DD;
#pragma unroll
    for (int kk = 0; kk < 4; ++kk) {
#pragma unroll
      for (int t = 0; t < 2; ++t) {
        int col = n0 + 16 * t + m16;
        bfrag[mat][kk][t] =
            *reinterpret_cast<const short8*>(WT + (size_t)col * DD + kk * 32 + kq * 8);
      }
    }
  }

  floatx4 acc[4][2];
#pragma unroll
  for (int rt = 0; rt < 4; ++rt)
#pragma unroll
    for (int t = 0; t < 2; ++t) acc[rt][t] = (floatx4){0.f, 0.f, 0.f, 0.f};

#pragma unroll
  for (int mat = 0; mat < 2; ++mat) {
    const unsigned short* A = mat ? Ah : Aself;
#pragma unroll
    for (int kk = 0; kk < 4; ++kk) {
#pragma unroll
      for (int rt = 0; rt < 4; ++rt) {
        int row = row0 + rt * 16 + m16;
        short8 af = *reinterpret_cast<const short8*>(A + (size_t)row * DD + kk * 32 + kq * 8);
        acc[rt][0] = __builtin_amdgcn_mfma_f32_16x16x32_bf16(af, bfrag[mat][kk][0], acc[rt][0], 0, 0, 0);
        acc[rt][1] = __builtin_amdgcn_mfma_f32_16x16x32_bf16(af, bfrag[mat][kk][1], acc[rt][1], 0, 0, 0);
      }
    }
  }

  float bs0 = bias[s * OO + n0 + m16];
  float bs1 = bias[s * OO + n0 + 16 + m16];
  float* outd = out + (size_t)d * NN * OO;
  if (!offdiag) {
#pragma unroll
    for (int rt = 0; rt < 4; ++rt) {
#pragma unroll
      for (int r = 0; r < 4; ++r) {
        int row = row0 + rt * 16 + kq * 4 + r;
        outd[(size_t)row * OO + n0 + m16] = acc[rt][0][r] + bs0;
        outd[(size_t)row * OO + n0 + 16 + m16] = acc[rt][1][r] + bs1;
      }
    }
  } else {
    const int* mg = merge + ((size_t)s * PN + d) * MM;
#pragma unroll
    for (int rt = 0; rt < 4; ++rt) {
#pragma unroll
      for (int r = 0; r < 4; ++r) {
        int row = row0 + rt * 16 + kq * 4 + r;
        int u = mg[row];
        atomicAdd(&outd[(size_t)u * OO + n0 + m16], acc[rt][0][r] + bs0);
        atomicAdd(&outd[(size_t)u * OO + n0 + 16 + m16], acc[rt][1][r] + bs1);
      }
    }
  }
}

extern "C" void kernel_launch(void* const* d_in, const int* in_sizes, int n_in,
                              void* d_out, int out_size, void* d_ws, size_t ws_size,
                              hipStream_t stream) {
  const float* feats = (const float*)d_in[0];
  const float* Wself = (const float*)d_in[1];
  const float* Wneigh = (const float*)d_in[2];
  const float* bias = (const float*)d_in[3];
  const int* esrc = (const int*)d_in[4];
  const int* edst = (const int*)d_in[5];
  const int* merge = (const int*)d_in[6];
  float* out = (float*)d_out;

  char* ws = (char*)d_ws;
  unsigned short* featsbf = (unsigned short*)(ws);               // 67,108,864
  int* deg   = (int*)(ws + 67108864);                            //  4,194,304
  int* offs  = (int*)(ws + 71303168);                            //  4,194,304
  int* csr   = (int*)(ws + 75497472);                            // 32,000,000
  unsigned short* hbuf = (unsigned short*)(ws + 107497472);      // 167,772,160 (ends 275,269,632)
  unsigned short* Wpack = (unsigned short*)(ws + 275269632);     //     262,144
  int* btot  = (int*)(ws + 275531776);                           //      16,384
  int* bbase = (int*)(ws + 275548160);                           //      16,384 (total 275,564,544)
  // overlays inside hbuf region (consumed before agg writes hbuf):
  uint2* tmp = (uint2*)(ws + 107497472);                         //  64,000,000
  int* mat   = (int*)(ws + 107497472 + 64000000);                //  16,056,320

  cvt_kernel<<<(PN * NN * DD) / 4 / 256, 256, 0, stream>>>(feats, featsbf);
  packW_kernel<<<512, 256, 0, stream>>>(Wself, Wneigh, Wpack);
  bucket_count<<<dim3(NW, 16), 256, 0, stream>>>(edst, mat);
  bucket_colscan<<<1024, 256, 0, stream>>>(mat, btot);
  bucket_base<<<16, 256, 0, stream>>>(btot, bbase);
  bucket_scatter<<<dim3(NW, 16), 256, 0, stream>>>(esrc, edst, mat, bbase, tmp);
  csr_build<<<dim3(256, 16), 256, 0, stream>>>(tmp, btot, bbase, deg, offs, csr);
  agg_kernel<<<dim3(NN / 4, 16), 256, 0, stream>>>(featsbf, csr, offs, deg, hbuf);
  // diag first: plain writes cover all of d_out; then off-diag atomically merges
  gemm_kernel<<<dim3(NN / 64, 4), 256, 0, stream>>>(featsbf, hbuf, Wpack, bias, merge, out, 0);
  gemm_kernel<<<dim3(MM / 64, 12), 256, 0, stream>>>(featsbf, hbuf, Wpack, bias, merge, out, 1);
}

// Round 2
// 1029.356 us; speedup vs baseline: 1.0095x; 1.0095x over previous
//
#include <hip/hip_runtime.h>
#include <stdint.h>

#define PN 4
#define NN 65536
#define DD 128
#define OO 128
#define EE 500000
#define MM 32768
#define NW 245       // WGs per block for bucketing: ceil(500000/2048)

typedef __attribute__((ext_vector_type(8))) short short8;
typedef __attribute__((ext_vector_type(4))) float floatx4;

__device__ __forceinline__ unsigned short f2bf(float f) {
  unsigned u = __float_as_uint(f);
  u += 0x7fffu + ((u >> 16) & 1u);
  return (unsigned short)(u >> 16);
}
__device__ __forceinline__ float bfhi2f(unsigned u) { return __uint_as_float(u & 0xffff0000u); }
__device__ __forceinline__ float bflo2f(unsigned u) { return __uint_as_float(u << 16); }

// block b = s*4+d; diag blocks are b in {0,5,10,15}
__device__ __forceinline__ long rowbase(int b) {
  int diagb = (b + 4) / 5;
  int offb = b - diagb;
  return (long)diagb * NN + (long)offb * MM;
}

// ---- fp32 -> bf16 conversion of feats ----
__global__ __launch_bounds__(256) void cvt_kernel(const float* __restrict__ f,
                                                  unsigned short* __restrict__ o) {
  size_t i = (size_t)blockIdx.x * blockDim.x + threadIdx.x;
  float4 v = ((const float4*)f)[i];
  uint2 r;
  r.x = ((unsigned)f2bf(v.y) << 16) | f2bf(v.x);
  r.y = ((unsigned)f2bf(v.w) << 16) | f2bf(v.z);
  ((uint2*)o)[i] = r;
}

// ---- pack W_self/W_neigh to bf16, col-major [mat][s][col][k] ----
__global__ __launch_bounds__(256) void packW_kernel(const float* __restrict__ Ws,
                                                    const float* __restrict__ Wn,
                                                    unsigned short* __restrict__ Wp) {
  int i = blockIdx.x * 256 + threadIdx.x;   // 2*4*128*128 = 131072
  int k = i & 127;
  int col = (i >> 7) & 127;
  int s = (i >> 14) & 3;
  int mat = i >> 16;
  const float* W = mat ? Wn : Ws;
  Wp[i] = f2bf(W[((size_t)s * DD + k) * OO + col]);
}

// ---- R1: per-WG coarse histogram (dst>>8), LDS only, coalesced matrix write ----
__global__ __launch_bounds__(256) void bucket_count(const int* __restrict__ edst,
                                                    int* __restrict__ mat) {
  __shared__ int hist[256];
  int b = blockIdx.y, w = blockIdx.x, t = threadIdx.x;
  hist[t] = 0;
  __syncthreads();
  size_t ebase = (size_t)b * EE;
#pragma unroll
  for (int k = 0; k < 8; ++k) {
    int e = w * 2048 + k * 256 + t;
    if (e < EE) atomicAdd(&hist[edst[ebase + e] >> 8], 1);
  }
  __syncthreads();
  mat[((size_t)b * NW + w) * 256 + t] = hist[t];
}

// ---- R2a: exclusive scan of mat over WG axis (per b,beta); totals per bucket ----
__global__ __launch_bounds__(256) void bucket_colscan(int* __restrict__ mat,
                                                      int* __restrict__ btot) {
  int t = threadIdx.x;
  int wid = blockIdx.x * 4 + (t >> 6);   // 4096 waves = 16 b * 256 beta
  int l = t & 63;
  int b = wid >> 8, beta = wid & 255;
  int run = 0;
  for (int c = 0; c < 4; ++c) {
    int w = c * 64 + l;
    size_t idx = ((size_t)b * NW + w) * 256 + beta;
    int v = (w < NW) ? mat[idx] : 0;
    int x = v;
#pragma unroll
    for (int off = 1; off < 64; off <<= 1) {
      int y = __shfl_up(x, off);
      if (l >= off) x += y;
    }
    if (w < NW) mat[idx] = run + x - v;
    run += __shfl(x, 63);
  }
  if (l == 0) btot[b * 256 + beta] = run;
}

// ---- R2b: per-block exclusive scan of 256 bucket totals -> bucket bases ----
__global__ __launch_bounds__(256) void bucket_base(const int* __restrict__ btot,
                                                   int* __restrict__ bbase) {
  __shared__ int sc[256];
  int b = blockIdx.x, t = threadIdx.x;
  int v = btot[b * 256 + t];
  sc[t] = v;
  __syncthreads();
  for (int off = 1; off < 256; off <<= 1) {
    int x = (t >= off) ? sc[t - off] : 0;
    __syncthreads();
    sc[t] += x;
    __syncthreads();
  }
  bbase[b * 256 + t] = sc[t] - v;
}

// ---- R3: scatter edges into coarse-bucket-sorted tmp via LDS cursors ----
__global__ __launch_bounds__(256) void bucket_scatter(const int* __restrict__ esrc,
                                                      const int* __restrict__ edst,
                                                      const int* __restrict__ mat,
                                                      const int* __restrict__ bbase,
                                                      uint2* __restrict__ tmp) {
  __shared__ int cur[256];
  int b = blockIdx.y, w = blockIdx.x, t = threadIdx.x;
  cur[t] = bbase[b * 256 + t] + mat[((size_t)b * NW + w) * 256 + t];
  __syncthreads();
  size_t ebase = (size_t)b * EE;
#pragma unroll
  for (int k = 0; k < 8; ++k) {
    int e = w * 2048 + k * 256 + t;
    if (e < EE) {
      int dv = edst[ebase + e];
      int sv = esrc[ebase + e];
      int p = atomicAdd(&cur[dv >> 8], 1);
      tmp[ebase + p] = (uint2){(unsigned)dv, (unsigned)sv};
    }
  }
}

// ---- R4: per (b, coarse bucket): fine CSR + deg + offs, all LDS-local ----
__global__ __launch_bounds__(256) void csr_build(const uint2* __restrict__ tmp,
                                                 const int* __restrict__ btot,
                                                 const int* __restrict__ bbase,
                                                 int* __restrict__ deg,
                                                 int* __restrict__ offs,
                                                 int* __restrict__ csr) {
  __shared__ int hist[256], sc[256], cur[256];
  int b = blockIdx.y, beta = blockIdx.x, t = threadIdx.x;
  int cnt = btot[b * 256 + beta];
  int segbase = bbase[b * 256 + beta];
  hist[t] = 0;
  __syncthreads();
  size_t tbase = (size_t)b * EE + segbase;
  for (int i = t; i < cnt; i += 256) atomicAdd(&hist[tmp[tbase + i].x & 255], 1);
  __syncthreads();
  sc[t] = hist[t];
  __syncthreads();
  for (int off = 1; off < 256; off <<= 1) {
    int x = (t >= off) ? sc[t - off] : 0;
    __syncthreads();
    sc[t] += x;
    __syncthreads();
  }
  int excl = sc[t] - hist[t];
  int v = beta * 256 + t;
  deg[b * NN + v] = hist[t];
  offs[b * NN + v] = segbase + excl;
  cur[t] = excl;
  __syncthreads();
  for (int i = t; i < cnt; i += 256) {
    uint2 pr = tmp[tbase + i];
    int p = atomicAdd(&cur[pr.x & 255], 1);
    csr[(size_t)b * EE + segbase + p] = (int)pr.y;
  }
}

// ---- mean aggregation: one wave per dst row ----
// Wave-uniform CSR segment; row indices moved to SGPRs via v_readlane so the
// feature-row base is SALU-computed (uniform base + l*4 voffset).
// NOTE (R1 post-mortem): VALUBusy 67->51% but dur unchanged -> bound on the
// L2-miss path (834 MB FETCH @ ~2.8 TB/s), which is within ~1.6x of the
// XCD-replication structural floor (8 XCDs x 16 MB x 4 partitions).
__global__ __launch_bounds__(256) void agg_kernel(const unsigned short* __restrict__ featsbf,
                                                  const int* __restrict__ csr,
                                                  const int* __restrict__ offs,
                                                  const int* __restrict__ deg,
                                                  unsigned short* __restrict__ hbuf) {
  int b = blockIdx.y;
  int s = b >> 2, d = b & 3;
  int num_dst = (s == d) ? NN : MM;
  int v = blockIdx.x * 4 + (threadIdx.x >> 6);
  if (v >= num_dst) return;
  int l = threadIdx.x & 63;
  const unsigned* F = (const unsigned*)(featsbf + (size_t)s * NN * DD);
  int o  = __builtin_amdgcn_readfirstlane(offs[b * NN + v]);
  int dg = __builtin_amdgcn_readfirstlane(deg[b * NN + v]);
  const int* cs = csr + (size_t)b * EE + o;   // wave-uniform pointer

  float alo[4] = {0.f, 0.f, 0.f, 0.f};
  float ahi[4] = {0.f, 0.f, 0.f, 0.f};

  for (int base = 0; base < dg; base += 64) {
    int rem = dg - base;
    int cnt = rem < 64 ? rem : 64;
    int myidx = (l < cnt) ? cs[base + l] : 0;
    int j = 0;
    for (; j + 8 <= cnt; j += 8) {
      unsigned p[8];
#pragma unroll
      for (int q = 0; q < 8; ++q) {
        int idx = __builtin_amdgcn_readlane(myidx, j + q);   // SGPR index
        p[q] = F[(size_t)idx * 64 + l];                      // uniform base + l*4
      }
#pragma unroll
      for (int q = 0; q < 8; ++q) { alo[q & 3] += bflo2f(p[q]); ahi[q & 3] += bfhi2f(p[q]); }
    }
    for (; j + 4 <= cnt; j += 4) {
      unsigned p[4];
#pragma unroll
      for (int q = 0; q < 4; ++q) {
        int idx = __builtin_amdgcn_readlane(myidx, j + q);
        p[q] = F[(size_t)idx * 64 + l];
      }
#pragma unroll
      for (int q = 0; q < 4; ++q) { alo[q] += bflo2f(p[q]); ahi[q] += bfhi2f(p[q]); }
    }
    for (; j < cnt; ++j) {
      int idx = __builtin_amdgcn_readlane(myidx, j);
      unsigned p = F[(size_t)idx * 64 + l];
      alo[0] += bflo2f(p); ahi[0] += bfhi2f(p);
    }
  }

  float a0 = (alo[0] + alo[1]) + (alo[2] + alo[3]);
  float a1 = (ahi[0] + ahi[1]) + (ahi[2] + ahi[3]);
  float inv = 1.0f / (float)(dg > 0 ? dg : 1);
  a0 *= inv; a1 *= inv;
  unsigned pk = ((unsigned)f2bf(a1) << 16) | f2bf(a0);
  ((unsigned*)hbuf)[(rowbase(b) + v) * 64 + l] = pk;
}

// ---- fused dual GEMM + merge epilogue ----
// mfma_f32_16x16x32_bf16: A[m=l&15][k=(l>>4)*8+j], B[k][n=l&15], C col=l&15, row=(l>>4)*4+reg
// Off-diag merge is ATOMIC-FREE: merge_idx is unique within each (s,d) block,
// so collisions only occur across blocks sharing d. The 12 off-diag blocks are
// partitioned into 3 stream-serialized rounds via the latin square
// d = (s+1+round)%4 -- within a round every block has distinct s and distinct d,
// so plain load+add+store RMW is race-free.
__global__ __launch_bounds__(256) void gemm_kernel(const unsigned short* __restrict__ featsbf,
                                                   const unsigned short* __restrict__ hbuf,
                                                   const unsigned short* __restrict__ Wpack,
                                                   const float* __restrict__ bias,
                                                   const int* __restrict__ merge,
                                                   float* __restrict__ out,
                                                   int offdiag, int round) {
  int w = threadIdx.x >> 6;
  int l = threadIdx.x & 63;
  int s, d;
  if (!offdiag) { d = blockIdx.y; s = d; }
  else { s = blockIdx.y; d = (s + 1 + round) & 3; }
  int b = s * 4 + d;
  int row0 = blockIdx.x * 64;
  int kq = l >> 4;
  int m16 = l & 15;
  int n0 = w * 32;

  const unsigned short* Aself = featsbf + (size_t)s * NN * DD;
  const unsigned short* Ah = hbuf + (size_t)rowbase(b) * DD;

  short8 bfrag[2][4][2];
#pragma unroll
  for (int mat = 0; mat < 2; ++mat) {
    const unsigned short* WT = Wpack + ((size_t)(mat * PN + s) * OO) * DD;
#pragma unroll
    for (int kk = 0; kk < 4; ++kk) {
#pragma unroll
      for (int t = 0; t < 2; ++t) {
        int col = n0 + 16 * t + m16;
        bfrag[mat][kk][t] =
            *reinterpret_cast<const short8*>(WT + (size_t)col * DD + kk * 32 + kq * 8);
      }
    }
  }

  floatx4 acc[4][2];
#pragma unroll
  for (int rt = 0; rt < 4; ++rt)
#pragma unroll
    for (int t = 0; t < 2; ++t) acc[rt][t] = (floatx4){0.f, 0.f, 0.f, 0.f};

#pragma unroll
  for (int mat = 0; mat < 2; ++mat) {
    const unsigned short* A = mat ? Ah : Aself;
#pragma unroll
    for (int kk = 0; kk < 4; ++kk) {
#pragma unroll
      for (int rt = 0; rt < 4; ++rt) {
        int row = row0 + rt * 16 + m16;
        short8 af = *reinterpret_cast<const short8*>(A + (size_t)row * DD + kk * 32 + kq * 8);
        acc[rt][0] = __builtin_amdgcn_mfma_f32_16x16x32_bf16(af, bfrag[mat][kk][0], acc[rt][0], 0, 0, 0);
        acc[rt][1] = __builtin_amdgcn_mfma_f32_16x16x32_bf16(af, bfrag[mat][kk][1], acc[rt][1], 0, 0, 0);
      }
    }
  }

  float bs0 = bias[s * OO + n0 + m16];
  float bs1 = bias[s * OO + n0 + 16 + m16];
  float* outd = out + (size_t)d * NN * OO;
  if (!offdiag) {
#pragma unroll
    for (int rt = 0; rt < 4; ++rt) {
#pragma unroll
      for (int r = 0; r < 4; ++r) {
        int row = row0 + rt * 16 + kq * 4 + r;
        outd[(size_t)row * OO + n0 + m16] = acc[rt][0][r] + bs0;
        outd[(size_t)row * OO + n0 + 16 + m16] = acc[rt][1][r] + bs1;
      }
    }
  } else {
    const int* mg = merge + ((size_t)s * PN + d) * MM;
#pragma unroll
    for (int rt = 0; rt < 4; ++rt) {
#pragma unroll
      for (int r = 0; r < 4; ++r) {
        int row = row0 + rt * 16 + kq * 4 + r;
        int u = mg[row];
        float* p0 = &outd[(size_t)u * OO + n0 + m16];
        float* p1 = &outd[(size_t)u * OO + n0 + 16 + m16];
        *p0 = *p0 + acc[rt][0][r] + bs0;   // race-free: unique u within (s,d),
        *p1 = *p1 + acc[rt][1][r] + bs1;   // one block per d per round
      }
    }
  }
}

extern "C" void kernel_launch(void* const* d_in, const int* in_sizes, int n_in,
                              void* d_out, int out_size, void* d_ws, size_t ws_size,
                              hipStream_t stream) {
  const float* feats = (const float*)d_in[0];
  const float* Wself = (const float*)d_in[1];
  const float* Wneigh = (const float*)d_in[2];
  const float* bias = (const float*)d_in[3];
  const int* esrc = (const int*)d_in[4];
  const int* edst = (const int*)d_in[5];
  const int* merge = (const int*)d_in[6];
  float* out = (float*)d_out;

  char* ws = (char*)d_ws;
  unsigned short* featsbf = (unsigned short*)(ws);               // 67,108,864
  int* deg   = (int*)(ws + 67108864);                            //  4,194,304
  int* offs  = (int*)(ws + 71303168);                            //  4,194,304
  int* csr   = (int*)(ws + 75497472);                            // 32,000,000
  unsigned short* hbuf = (unsigned short*)(ws + 107497472);      // 167,772,160 (ends 275,269,632)
  unsigned short* Wpack = (unsigned short*)(ws + 275269632);     //     262,144
  int* btot  = (int*)(ws + 275531776);                           //      16,384
  int* bbase = (int*)(ws + 275548160);                           //      16,384 (total 275,564,544)
  // overlays inside hbuf region (consumed before agg writes hbuf):
  uint2* tmp = (uint2*)(ws + 107497472);                         //  64,000,000
  int* mat   = (int*)(ws + 107497472 + 64000000);                //  16,056,320

  cvt_kernel<<<(PN * NN * DD) / 4 / 256, 256, 0, stream>>>(feats, featsbf);
  packW_kernel<<<512, 256, 0, stream>>>(Wself, Wneigh, Wpack);
  bucket_count<<<dim3(NW, 16), 256, 0, stream>>>(edst, mat);
  bucket_colscan<<<1024, 256, 0, stream>>>(mat, btot);
  bucket_base<<<16, 256, 0, stream>>>(btot, bbase);
  bucket_scatter<<<dim3(NW, 16), 256, 0, stream>>>(esrc, edst, mat, bbase, tmp);
  csr_build<<<dim3(256, 16), 256, 0, stream>>>(tmp, btot, bbase, deg, offs, csr);
  agg_kernel<<<dim3(NN / 4, 16), 256, 0, stream>>>(featsbf, csr, offs, deg, hbuf);
  // diag first: plain writes cover all of d_out; then 3 atomic-free merge rounds
  gemm_kernel<<<dim3(NN / 64, 4), 256, 0, stream>>>(featsbf, hbuf, Wpack, bias, merge, out, 0, 0);
  gemm_kernel<<<dim3(MM / 64, 4), 256, 0, stream>>>(featsbf, hbuf, Wpack, bias, merge, out, 1, 0);
  gemm_kernel<<<dim3(MM / 64, 4), 256, 0, stream>>>(featsbf, hbuf, Wpack, bias, merge, out, 1, 1);
  gemm_kernel<<<dim3(MM / 64, 4), 256, 0, stream>>>(featsbf, hbuf, Wpack, bias, merge, out, 1, 2);
}